// Round 9
// baseline (587.110 us; speedup 1.0000x reference)
//
#include <hip/hip_runtime.h>
#include <stdint.h>

typedef __bf16 bf16_t;
typedef __bf16 bf16x8 __attribute__((ext_vector_type(8)));
typedef float  f32x4  __attribute__((ext_vector_type(4)));

union Frag { uint32_t u[4]; bf16x8 v; };

struct WPtrs {
    const float* Wi[4];
    const float* Wh[4];
    const float* bi[4];
    const float* bh[4];
};

#define LOG2E 1.44269504088896340736f

// Gate pre-activations arrive PRE-SCALED: i,f,o by log2e; g by 2*log2e
// (folded into bf16 weight fragments + biases at build time).
// Shared-rcp cell algebra: one rcp per c-update, one per h-update.
__device__ __forceinline__ float cell_c(float gi, float gf, float gg, float c) {
    const float ef = __builtin_amdgcn_exp2f(-gf);
    const float ei = __builtin_amdgcn_exp2f(-gi);
    const float Eg = __builtin_amdgcn_exp2f(gg);
    const float pf = 1.0f + ef, pi = 1.0f + ei;
    const float pg = Eg + 1.0f, mg = Eg - 1.0f;
    const float num = c * pi * pg + mg * pf;
    const float den = pf * pi * pg;
    return num * __builtin_amdgcn_rcpf(den);
}
__device__ __forceinline__ float cell_h(float go, float c) {
    const float Ec = __builtin_amdgcn_exp2f(c * (2.0f * LOG2E));
    const float eo = __builtin_amdgcn_exp2f(-go);
    const float num = Ec - 1.0f;
    const float den = (1.0f + eo) * (Ec + 1.0f);
    return num * __builtin_amdgcn_rcpf(den);
}

// Half-swap within each 16-lane DPP row: lane i <-> lane i^8 (row_ror:8).
__device__ __forceinline__ float dpp_halfswap(float x) {
    int i = __float_as_int(x);
    int r = __builtin_amdgcn_update_dpp(i, i, 0x128 /*row_ror:8*/, 0xF, 0xF, false);
    return __int_as_float(r);
}

// Phase barrier WITHOUT the vmcnt(0) drain of __syncthreads (T4 analog):
// LDS correctness needs only lgkmcnt(0) (drains this phase's ds_reads for the
// WAR hazard and ds_writes for the RAW hazard); global x-prefetch loads stay
// in flight across the barrier (consumed via compiler-counted vmcnt at use,
// 2 phases later). "memory"-clobbered asm on both sides pins LDS-op ordering.
__device__ __forceinline__ void phase_barrier() {
    asm volatile("s_waitcnt lgkmcnt(0)" ::: "memory");
    __builtin_amdgcn_s_barrier();
    asm volatile("" ::: "memory");
}

// Fused 4-layer LSTM, layer-pipelined across 16 waves (structure HW-verified r4-r8).
// Grid 256 blocks = batch tiles of 8 (MFMA N=16, cols 8..15 pad; pad lanes
// repurposed via DPP half-swap so all 64 lanes compute 2 REAL cells).
// Block 1024 thr = 16 waves; wave w: layer l=w>>2, unit-quarter uq=w&3.
// Phase p: layer l computes t=p-l; 1 barrier/phase; lds_h double-buffered.
//
// r9 vs r8 — ONE change: per-phase __syncthreads() -> phase_barrier()
// (lgkmcnt-only drain + raw s_barrier). __syncthreads' implicit vmcnt(0)
// was draining layer-0's depth-2 x prefetch (first-touch HBM, ~900 cyc)
// inside every phase and convoying all 16 waves behind it.
__global__ __launch_bounds__(1024, 4)
void lstm_fused(const float* __restrict__ x0, float* __restrict__ last_out, WPtrs wp)
{
    const int tile = blockIdx.x;
    const int tid  = threadIdx.x;
    const int w    = tid >> 6;
    const int lane = tid & 63;
    const int l15  = lane & 15;
    const int l4   = lane >> 4;
    const int l    = w >> 2;
    const int uq   = w & 3;
    const bool hiH = (l15 >= 8);
    const int  col = l15 & 7;

    // [buf][layer][laneIdx][ut 0..3 + 2 pad] ; laneIdx = 16*l4 + col ; 24 KB
    __shared__ uint2 lds_h[2][4][64][6];

    for (int i = tid; i < 2 * 4 * 64 * 6; i += 1024)
        ((uint2*)lds_h)[i] = make_uint2(0u, 0u);

    const float* Wi = wp.Wi[l];
    const float* Wh = wp.Wh[l];

    // per-gate prescale: i,f,o -> log2e ; g -> 2*log2e
    const float gs[4] = {LOG2E, LOG2E, 2.0f * LOG2E, LOG2E};

    // ---- weight A-fragments (loop-invariant registers) ----
    // A-frag lane map (HW-verified): row = base + l15, k = 32*s + 4*l4 + j (+16 for j>=4)
    bf16x8 whA[4][2];
    bf16x8 wiA[4][2];
#pragma unroll
    for (int G = 0; G < 4; ++G) {
        const float sc = gs[G];
        const int row = G * 64 + 16 * uq + l15;
        const float* r = Wh + (size_t)row * 64;
#pragma unroll
        for (int s = 0; s < 2; ++s) {
            f32x4 a = *(const f32x4*)(r + 32 * s + 4 * l4);
            f32x4 b = *(const f32x4*)(r + 32 * s + 4 * l4 + 16);
            bf16x8 f;
            f[0] = (bf16_t)(a[0] * sc); f[1] = (bf16_t)(a[1] * sc);
            f[2] = (bf16_t)(a[2] * sc); f[3] = (bf16_t)(a[3] * sc);
            f[4] = (bf16_t)(b[0] * sc); f[5] = (bf16_t)(b[1] * sc);
            f[6] = (bf16_t)(b[2] * sc); f[7] = (bf16_t)(b[3] * sc);
            whA[G][s] = f;
        }
        if (l == 0) {
            const float* ri = Wi + (size_t)row * 18;     // K=18 padded to 32
            const int k0 = 4 * l4;
            bf16x8 f;
            f[0] = (bf16_t)(ri[k0 + 0] * sc); f[1] = (bf16_t)(ri[k0 + 1] * sc);
            f[2] = (bf16_t)(ri[k0 + 2] * sc); f[3] = (bf16_t)(ri[k0 + 3] * sc);
            f[4] = (l4 == 0) ? (bf16_t)(ri[16] * sc) : (bf16_t)0.0f;
            f[5] = (l4 == 0) ? (bf16_t)(ri[17] * sc) : (bf16_t)0.0f;
            f[6] = (bf16_t)0.0f; f[7] = (bf16_t)0.0f;
            wiA[G][0] = f;
            wiA[G][1] = f;   // placeholder; [2][1]/[3][1] become x buffers below
        } else {
            const float* ri = Wi + (size_t)row * 64;
#pragma unroll
            for (int s = 0; s < 2; ++s) {
                f32x4 a = *(const f32x4*)(ri + 32 * s + 4 * l4);
                f32x4 b = *(const f32x4*)(ri + 32 * s + 4 * l4 + 16);
                bf16x8 f;
                f[0] = (bf16_t)(a[0] * sc); f[1] = (bf16_t)(a[1] * sc);
                f[2] = (bf16_t)(a[2] * sc); f[3] = (bf16_t)(a[3] * sc);
                f[4] = (bf16_t)(b[0] * sc); f[5] = (bf16_t)(b[1] * sc);
                f[6] = (bf16_t)(b[2] * sc); f[7] = (bf16_t)(b[3] * sc);
                wiA[G][s] = f;
            }
        }
    }

    // ---- bias: ONLY the 8 post-swap scalars this lane consumes ----
    float biasA[4], biasB[4];
#pragma unroll
    for (int G = 0; G < 4; ++G) {
        const int rb = G * 64 + 16 * uq + 4 * l4 + (hiH ? 2 : 0);
        biasA[G] = (wp.bi[l][rb]     + wp.bh[l][rb])     * gs[G];
        biasB[G] = (wp.bi[l][rb + 1] + wp.bh[l][rb + 1]) * gs[G];
    }

    // ---- x prefetch (layer-0 waves), depth 2 ----
    // ALIASED onto wiA[2][1] / wiA[3][1]: dead slots for l==0, untouched by l>0.
    bf16x8& xfA = wiA[2][1];
    bf16x8& xfB = wiA[3][1];
    const int    xbatch = tile * 8 + (hiH ? 7 : col);
    const float* xrow   = x0 + (size_t)xbatch * (512 * 18);
    auto loadx = [&](int t, bf16x8& dst) {
        const float* xr = xrow + t * 18;
        const int k0 = 4 * l4;
        bf16x8 f;
        f[0] = (bf16_t)xr[k0 + 0]; f[1] = (bf16_t)xr[k0 + 1];
        f[2] = (bf16_t)xr[k0 + 2]; f[3] = (bf16_t)xr[k0 + 3];
        f[4] = (l4 == 0) ? (bf16_t)xr[16] : (bf16_t)0.0f;
        f[5] = (l4 == 0) ? (bf16_t)xr[17] : (bf16_t)0.0f;
        f[6] = (bf16_t)0.0f; f[7] = (bf16_t)0.0f;
        dst = f;
    };
    if (l == 0) { loadx(0, xfA); loadx(1, xfB); }

    float c0 = 0.0f, c1 = 0.0f;     // 2 real cells/lane

    __syncthreads();    // once, pre-loop: full drain is fine here

    // br/bw arrive as LITERAL constants from the unrolled call sites.
    auto phase = [&](int p, int br, int bw, bf16x8& xf) {
        const int t = p - l;
        if (t >= 0 && t < 512) {
            const f32x4 z4 = {0.0f, 0.0f, 0.0f, 0.0f};
            f32x4 acc[4];

            // ---- x contribution (C starts at zero; bias added post-DPP) ----
            if (l == 0) {
#pragma unroll
                for (int G = 0; G < 4; ++G)
                    acc[G] = __builtin_amdgcn_mfma_f32_16x16x32_bf16(wiA[G][0], xf, z4, 0, 0, 0);
                loadx((t + 2) & 511, xf);       // prefetch 2 ahead (wrap harmless)
            } else {
                Frag b0, b1;
                {
                    uint4 q0 = *(const uint4*)&lds_h[br][l - 1][lane][0];
                    uint4 q1 = *(const uint4*)&lds_h[br][l - 1][lane][2];
                    b0.u[0] = q0.x; b0.u[1] = q0.y; b0.u[2] = q0.z; b0.u[3] = q0.w;
                    b1.u[0] = q1.x; b1.u[1] = q1.y; b1.u[2] = q1.z; b1.u[3] = q1.w;
                }
#pragma unroll
                for (int G = 0; G < 4; ++G)
                    acc[G] = __builtin_amdgcn_mfma_f32_16x16x32_bf16(wiA[G][0], b0.v, z4, 0, 0, 0);
#pragma unroll
                for (int G = 0; G < 4; ++G)
                    acc[G] = __builtin_amdgcn_mfma_f32_16x16x32_bf16(wiA[G][1], b1.v, acc[G], 0, 0, 0);
            }

            // ---- h contribution (own layer, t-1): 2 x ds_read_b128 ----
            {
                Frag h0, h1;
                uint4 q0 = *(const uint4*)&lds_h[br][l][lane][0];
                uint4 q1 = *(const uint4*)&lds_h[br][l][lane][2];
                h0.u[0] = q0.x; h0.u[1] = q0.y; h0.u[2] = q0.z; h0.u[3] = q0.w;
                h1.u[0] = q1.x; h1.u[1] = q1.y; h1.u[2] = q1.z; h1.u[3] = q1.w;
#pragma unroll
                for (int G = 0; G < 4; ++G)
                    acc[G] = __builtin_amdgcn_mfma_f32_16x16x32_bf16(whA[G][0], h0.v, acc[G], 0, 0, 0);
#pragma unroll
                for (int G = 0; G < 4; ++G)
                    acc[G] = __builtin_amdgcn_mfma_f32_16x16x32_bf16(whA[G][1], h1.v, acc[G], 0, 0, 0);
            }

            // ---- DPP half-swap: every lane gets 2 REAL cells; add bias here ----
            float g0[4], g1[4];
#pragma unroll
            for (int G = 0; G < 4; ++G) {
                const float s2 = dpp_halfswap(acc[G][2]);
                const float s3 = dpp_halfswap(acc[G][3]);
                g0[G] = (hiH ? s2 : acc[G][0]) + biasA[G];
                g1[G] = (hiH ? s3 : acc[G][1]) + biasB[G];
            }

            // ---- cell update (shared-rcp, prescaled gates) ----
            const float cA = cell_c(g0[0], g0[1], g0[2], c0);
            const float cB = cell_c(g1[0], g1[1], g1[2], c1);
            c0 = cA; c1 = cB;
            const float hA = cell_h(g0[3], cA);
            const float hB = cell_h(g1[3], cB);

            // ---- h writeback: one b32 per lane; pad laneIdx slots never written ----
            union { uint32_t u; bf16_t b[2]; } pk;
            pk.b[0] = (bf16_t)hA; pk.b[1] = (bf16_t)hB;
            uint32_t* slot = (uint32_t*)&lds_h[bw][l][16 * l4 + col][uq];
            slot[hiH ? 1 : 0] = pk.u;

            if (l == 3 && t == 511) {
                float* o = last_out + ((size_t)(tile * 8 + col)) * 64
                           + 16 * uq + 4 * l4 + (hiH ? 2 : 0);
                *(float2*)o = make_float2(hA, hB);
            }
        }
        phase_barrier();
    };

    // 515 phases needed (t=511 for l=3 at p=514); rounded up to 516.
    for (int p = 0; p < 516; p += 2) {
        phase(p,     1, 0, xfA);      // even p: read buf1, write buf0
        phase(p + 1, 0, 1, xfB);      // odd  p: read buf0, write buf1
    }
}

// out = relu(last @ W1^T + b1) @ W2^T + b2   (f32, tiny)
__global__ __launch_bounds__(256)
void mlp_head(const float* __restrict__ last,
              const float* __restrict__ W1, const float* __restrict__ b1,
              const float* __restrict__ W2, const float* __restrict__ b2,
              float* __restrict__ out)
{
    __shared__ float sW1[128 * 64];
    __shared__ float sb1[128];
    __shared__ float sW2[3 * 128];
    __shared__ float sb2[4];
    const int tid = threadIdx.x;
    for (int i = tid; i < 128 * 64; i += 256) sW1[i] = W1[i];
    for (int i = tid; i < 128; i += 256) sb1[i] = b1[i];
    for (int i = tid; i < 3 * 128; i += 256) sW2[i] = W2[i];
    if (tid < 3) sb2[tid] = b2[tid];
    __syncthreads();

    const int b = blockIdx.x * 256 + tid;
    const float* lb = last + (size_t)b * 64;
    float xv[64];
#pragma unroll
    for (int k = 0; k < 64; k += 4) {
        f32x4 v = *(const f32x4*)(lb + k);
        xv[k] = v[0]; xv[k + 1] = v[1]; xv[k + 2] = v[2]; xv[k + 3] = v[3];
    }
    float o0 = sb2[0], o1 = sb2[1], o2 = sb2[2];
    for (int j = 0; j < 128; ++j) {
        float a = sb1[j];
        const float* wr = &sW1[j * 64];
#pragma unroll
        for (int k = 0; k < 64; k += 4) {
            f32x4 wv = *(const f32x4*)(wr + k);
            a += xv[k] * wv[0] + xv[k + 1] * wv[1] + xv[k + 2] * wv[2] + xv[k + 3] * wv[3];
        }
        a = fmaxf(a, 0.0f);
        o0 += a * sW2[0 * 128 + j];
        o1 += a * sW2[1 * 128 + j];
        o2 += a * sW2[2 * 128 + j];
    }
    out[(size_t)b * 3 + 0] = o0;
    out[(size_t)b * 3 + 1] = o1;
    out[(size_t)b * 3 + 2] = o2;
}

extern "C" void kernel_launch(void* const* d_in, const int* in_sizes, int n_in,
                              void* d_out, int out_size, void* d_ws, size_t ws_size,
                              hipStream_t stream)
{
    (void)in_sizes; (void)n_in; (void)out_size; (void)ws_size;

    const float* x = (const float*)d_in[0];
    WPtrs wp;
    for (int l = 0; l < 4; ++l) {
        wp.Wi[l] = (const float*)d_in[1 + 4 * l + 0];
        wp.Wh[l] = (const float*)d_in[1 + 4 * l + 1];
        wp.bi[l] = (const float*)d_in[1 + 4 * l + 2];
        wp.bh[l] = (const float*)d_in[1 + 4 * l + 3];
    }
    const float* W1 = (const float*)d_in[17];
    const float* b1 = (const float*)d_in[18];
    const float* W2 = (const float*)d_in[19];
    const float* b2 = (const float*)d_in[20];

    float* last = (float*)d_ws;                 // 2048*64 f32 = 512 KiB

    lstm_fused<<<dim3(256), dim3(1024), 0, stream>>>(x, last, wp);
    mlp_head<<<dim3(8), dim3(256), 0, stream>>>(last, W1, b1, W2, b2, (float*)d_out);
}